// Round 9
// baseline (186.470 us; speedup 1.0000x reference)
//
#include <hip/hip_runtime.h>

#define WW 320           // input width/height
#define OWID 314         // output cols
#define OHEI 314         // output rows
#define BB 64            // batch
#define WPB 6            // waves per block (6*58 = 348 >= 314 cols covered)
#define NTH (WPB * 64)   // 384 threads
#define CW 58            // output cols OWNED per wave (lanes 58..63 = halo)
#define BROWS 79         // output rows per band
#define NBAND 4          // 4*79 = 316 >= 314; tail masked
#define NIN (BROWS + 6)  // 85 input rows streamed per band
#define NBLK (BB * NBAND)  // 256 blocks exactly = one per CU

// One input row step for this thread's column. Vertical ring of 4 combined
// moments {px=x0+x1, py=y0+y1, p2=x0^2+x1^2+y0^2+y1^2, pxy=x0*y0+x1*y1};
// horizontal 7-tap done across lanes with a shfl tree (lanes l..l+6).
// K_ is a literal (0..6) => ring indices static. I_ = i7 + K_ (uniform).
#define BODY(I_, K_)                                                          \
  {                                                                           \
    const int rr  = min(r0 + (I_), WW - 1);   /* clamp: band-3 tail masked */ \
    const int off = rr * WW;                  /* wave-uniform (SALU) */       \
    const float x0 = X0[off], x1 = X1[off];                                   \
    const float y0 = Y0[off], y1 = Y1[off];                                   \
    const float px  = x0 + x1;                                                \
    const float py  = y0 + y1;                                                \
    const float p2  = x0 * x0 + x1 * x1 + y0 * y0 + y1 * y1;                  \
    const float pxy = x0 * y0 + x1 * y1;                                      \
    V0 += px  - ring[K_][0]; ring[K_][0] = px;                                \
    V1 += py  - ring[K_][1]; ring[K_][1] = py;                                \
    V2 += p2  - ring[K_][2]; ring[K_][2] = p2;                                \
    V3 += pxy - ring[K_][3]; ring[K_][3] = pxy;                               \
    if ((I_) >= 6) {                                                          \
      const int t = r0 + (I_) - 6;            /* output row */                \
      if (t < OHEI) {                         /* uniform tail-band mask */    \
        /* H[l] = sum_{j=l..l+6} V[j]:  s2=a+a>>1; s4=s2+s2>>2;          */   \
        /* H = s4 + (s2>>4) + (a>>6)  — 4 shfl + 4 add per moment.       */   \
        float b0 = V0 + __shfl_down(V0, 1, 64);                               \
        float b1 = V1 + __shfl_down(V1, 1, 64);                               \
        float b2 = V2 + __shfl_down(V2, 1, 64);                               \
        float b3 = V3 + __shfl_down(V3, 1, 64);                               \
        float q0 = b0 + __shfl_down(b0, 2, 64);                               \
        float q1 = b1 + __shfl_down(b1, 2, 64);                               \
        float q2 = b2 + __shfl_down(b2, 2, 64);                               \
        float q3 = b3 + __shfl_down(b3, 2, 64);                               \
        float H0 = q0 + __shfl_down(b0, 4, 64) + __shfl_down(V0, 6, 64);      \
        float H1 = q1 + __shfl_down(b1, 4, 64) + __shfl_down(V1, 6, 64);      \
        float H2 = q2 + __shfl_down(b2, 4, 64) + __shfl_down(V2, 6, 64);      \
        float H3 = q3 + __shfl_down(b3, 4, 64) + __shfl_down(V3, 6, 64);      \
        const float ux  = H0 * inv, uy = H1 * inv;                            \
        const float u2  = H2 * inv, uxy = H3 * inv;                           \
        const float vxy = cn * (uxy - ux * uy);                               \
        const float v2m = cn * (u2 - ux * ux - uy * uy);   /* vx + vy */      \
        const float A1  = 2.0f * ux * uy + C1;                                \
        const float A2  = 2.0f * vxy + C2;                                    \
        const float B1  = ux * ux + uy * uy + C1;                             \
        const float B2  = v2m + C2;                                           \
        ssum += cmf * (A1 * A2) / (B1 * B2);  /* halo/dup lanes masked */     \
      }                                                                       \
    }                                                                         \
  }

// One output column per thread, vertical-first. 4 coalesced dword loads per
// row (wave = 256 B = 4 cache lines/load — minimal line touches; bytes/output
// 16.3 vs 45 for 4-col strips). No LDS in the loop, no barriers; horizontal
// via intra-wave shfl tree. Grid = 256 blocks = 1/CU, 6 waves each.
__global__ __launch_bounds__(NTH, 1) void ssim_main(
    const float* __restrict__ X, const float* __restrict__ Y,
    const float* __restrict__ dr, double* __restrict__ acc,
    unsigned* __restrict__ counter, float* __restrict__ out)
{
    const int w    = threadIdx.x >> 6;       // wave in block
    const int lane = threadIdx.x & 63;
    const int b    = blockIdx.x >> 2;        // image
    const int band = blockIdx.x & 3;
    const int r0   = band * BROWS;           // first output row of band

    int c = w * CW + lane;                   // column this lane loads
    const float cmf = (lane < CW && c < OWID) ? 1.0f : 0.0f;  // owner mask
    if (c > WW - 1) c = WW - 1;              // clamp halo loads in-bounds

    const size_t plane = (size_t)WW * WW;
    const float* X0 = X + (size_t)b * 2 * plane + c;
    const float* X1 = X0 + plane;
    const float* Y0 = Y + (size_t)b * 2 * plane + c;
    const float* Y1 = Y0 + plane;

    const float d  = dr[b];
    const float C1 = (0.01f * d) * (0.01f * d);
    const float C2 = (0.03f * d) * (0.03f * d);
    const float inv = 1.0f / 49.0f;
    const float cn  = 49.0f / 48.0f;

    float ring[7][4];                        // 28 regs — far below spill line
    #pragma unroll
    for (int k = 0; k < 7; ++k) {
        ring[k][0] = 0.0f; ring[k][1] = 0.0f;
        ring[k][2] = 0.0f; ring[k][3] = 0.0f;
    }
    float V0 = 0.0f, V1 = 0.0f, V2 = 0.0f, V3 = 0.0f;
    float ssum = 0.0f;

    // 85 input rows = 12 x 7 + 1; rolled outer loop (no live-range blowup),
    // 7-wide inner => ring slots are literals.
    #pragma unroll 1
    for (int i7 = 0; i7 < 84; i7 += 7) {
        BODY(i7 + 0, 0)
        BODY(i7 + 1, 1)
        BODY(i7 + 2, 2)
        BODY(i7 + 3, 3)
        BODY(i7 + 4, 4)
        BODY(i7 + 5, 5)
        BODY(i7 + 6, 6)
    }
    BODY(84, 0)                              // 84 % 7 == 0

    // ---- reduction: wave shuffle (double) -> LDS -> one atomic per block ----
    double local = (double)ssum;
    #pragma unroll
    for (int off = 32; off > 0; off >>= 1)
        local += __shfl_down(local, off, 64);
    __shared__ double wsum[WPB];
    if (lane == 0) wsum[w] = local;
    __syncthreads();
    if (threadIdx.x == 0) {
        double tot = 0.0;
        #pragma unroll
        for (int k = 0; k < WPB; ++k) tot += wsum[k];
        atomicAdd(acc, tot);
        __threadfence();
        unsigned ticket = atomicAdd(counter, 1u);
        if (ticket == NBLK - 1) {
            double stot = atomicAdd(acc, 0.0);   // device-scope coherent read
            const double N = (double)BB * (double)OHEI * (double)OWID;
            out[0] = (float)(1.0 - stot / N);
        }
    }
}

extern "C" void kernel_launch(void* const* d_in, const int* in_sizes, int n_in,
                              void* d_out, int out_size, void* d_ws, size_t ws_size,
                              hipStream_t stream)
{
    const float* X  = (const float*)d_in[0];
    const float* Y  = (const float*)d_in[1];
    const float* dr = (const float*)d_in[2];
    // d_in[3] is the box kernel w (all 1/49) — folded into constants.
    double*   acc     = (double*)d_ws;
    unsigned* counter = (unsigned*)((char*)d_ws + 8);
    float*    out     = (float*)d_out;

    hipMemsetAsync(d_ws, 0, 16, stream);
    ssim_main<<<dim3(NBLK), dim3(NTH), 0, stream>>>(X, Y, dr, acc, counter, out);
}

// Round 11
// 136.667 us; speedup vs baseline: 1.3644x; 1.3644x over previous
//
#include <hip/hip_runtime.h>

#define WW 320           // input width/height
#define OWID 314         // output cols
#define OHEI 314         // output rows
#define BB 64            // batch
#define CW 58            // output cols OWNED per wave (lanes 58..63 = halo)
#define NCW 6            // col-waves to cover 314 cols (6*58 = 348)
#define BROWS 40         // output rows per band
#define NBAND 8          // 8*40 = 320 >= 314; tail masked
#define BPB 2            // bands per block
#define WPB (NCW * BPB)  // 12 waves per block
#define NTH (WPB * 64)   // 768 threads
#define NBLK (BB * NBAND / BPB)   // 64*4 = 256 blocks = exactly 1/CU

// Batched group load: 4 scalar coalesced loads per row, 7 rows at once ->
// 28 loads in flight per wave (explicit MLP; compiler won't hoist past the
// SSIM div chain on its own — R9 evidence).
#define LOADR(K_)                                                             \
  {                                                                           \
    const int rr  = min(r0 + g7 + (K_), WW - 1);  /* clamp; tail masked */    \
    const int off = rr * WW;                      /* wave-uniform (SALU) */   \
    gx0[K_] = X0[off]; gx1[K_] = X1[off];                                     \
    gy0[K_] = Y0[off]; gy1[K_] = Y1[off];                                     \
  }

// One input row step: vertical ring of 4 combined moments, horizontal 7-tap
// across lanes via shfl tree (verified bit-exact in R9). K_ literal 0..6 and
// g7 % 7 == 0  =>  ring slot == K_ (static).
#define BODY(K_)                                                              \
  {                                                                           \
    const float x0 = gx0[K_], x1 = gx1[K_];                                   \
    const float y0 = gy0[K_], y1 = gy1[K_];                                   \
    const float px  = x0 + x1;                                                \
    const float py  = y0 + y1;                                                \
    const float p2  = x0 * x0 + x1 * x1 + y0 * y0 + y1 * y1;                  \
    const float pxy = x0 * y0 + x1 * y1;                                      \
    V0 += px  - ring[K_][0]; ring[K_][0] = px;                                \
    V1 += py  - ring[K_][1]; ring[K_][1] = py;                                \
    V2 += p2  - ring[K_][2]; ring[K_][2] = p2;                                \
    V3 += pxy - ring[K_][3]; ring[K_][3] = pxy;                               \
    const int i_ = g7 + (K_);                                                 \
    const int t  = r0 + i_ - 6;               /* output row */                \
    if (i_ >= 6 && t < tmax) {                /* wave-uniform mask */         \
      float b0 = V0 + __shfl_down(V0, 1, 64);                                 \
      float b1 = V1 + __shfl_down(V1, 1, 64);                                 \
      float b2 = V2 + __shfl_down(V2, 1, 64);                                 \
      float b3 = V3 + __shfl_down(V3, 1, 64);                                 \
      float q0 = b0 + __shfl_down(b0, 2, 64);                                 \
      float q1 = b1 + __shfl_down(b1, 2, 64);                                 \
      float q2 = b2 + __shfl_down(b2, 2, 64);                                 \
      float q3 = b3 + __shfl_down(b3, 2, 64);                                 \
      float H0 = q0 + __shfl_down(b0, 4, 64) + __shfl_down(V0, 6, 64);        \
      float H1 = q1 + __shfl_down(b1, 4, 64) + __shfl_down(V1, 6, 64);        \
      float H2 = q2 + __shfl_down(b2, 4, 64) + __shfl_down(V2, 6, 64);        \
      float H3 = q3 + __shfl_down(b3, 4, 64) + __shfl_down(V3, 6, 64);        \
      const float ux  = H0 * inv, uy = H1 * inv;                              \
      const float u2  = H2 * inv, uxy = H3 * inv;                             \
      const float vxy = cn * (uxy - ux * uy);                                 \
      const float v2m = cn * (u2 - ux * ux - uy * uy);   /* vx + vy */        \
      const float A1  = 2.0f * ux * uy + C1;                                  \
      const float A2  = 2.0f * vxy + C2;                                      \
      const float B1  = ux * ux + uy * uy + C1;                               \
      const float B2  = v2m + C2;                                             \
      ssum += cmf * (A1 * A2) / (B1 * B2);   /* halo/dup lanes masked */      \
    }                                                                         \
  }

// Transposed (one output column per thread), 12 waves per block: waves of one
// block are GUARANTEED co-resident (R1 showed extra blocks don't stack; R9
// showed intra-block waves do) -> 3 waves/SIMD of latency hiding, plus
// 28-deep batched loads per 7-row group.
__global__ __launch_bounds__(NTH, 1) void ssim_main(
    const float* __restrict__ X, const float* __restrict__ Y,
    const float* __restrict__ dr, double* __restrict__ acc,
    unsigned* __restrict__ counter, float* __restrict__ out)
{
    const int w    = threadIdx.x >> 6;        // wave in block (0..11)
    const int lane = threadIdx.x & 63;
    const int b    = blockIdx.x >> 2;         // image
    const int pair = blockIdx.x & 3;          // band pair
    const int band = pair * BPB + (w / NCW);  // this wave's band (0..7)
    const int r0   = band * BROWS;            // first output row of band
    const int tmax = min(r0 + BROWS, OHEI);   // band-exclusive output rows

    int c = (w % NCW) * CW + lane;            // column this lane loads
    const float cmf = (lane < CW && c < OWID) ? 1.0f : 0.0f;  // owner mask
    if (c > WW - 1) c = WW - 1;               // clamp halo loads in-bounds

    const size_t plane = (size_t)WW * WW;
    const float* X0 = X + (size_t)b * 2 * plane + c;
    const float* X1 = X0 + plane;
    const float* Y0 = Y + (size_t)b * 2 * plane + c;
    const float* Y1 = Y0 + plane;

    const float d  = dr[b];
    const float C1 = (0.01f * d) * (0.01f * d);
    const float C2 = (0.03f * d) * (0.03f * d);
    const float inv = 1.0f / 49.0f;
    const float cn  = 49.0f / 48.0f;

    float ring[7][4];                         // 28 regs
    #pragma unroll
    for (int k = 0; k < 7; ++k) {
        ring[k][0] = 0.0f; ring[k][1] = 0.0f;
        ring[k][2] = 0.0f; ring[k][3] = 0.0f;
    }
    float V0 = 0.0f, V1 = 0.0f, V2 = 0.0f, V3 = 0.0f;
    float ssum = 0.0f;
    float gx0[7], gx1[7], gy0[7], gy1[7];     // batched group buffer (28 regs)

    // 46 live input rows, run as 7 groups of 7 (49; overshoot masked by tmax).
    // Rolled outer loop (no live-range blowup); all ring/buffer idx literal.
    #pragma unroll 1
    for (int g7 = 0; g7 < 49; g7 += 7) {
        LOADR(0) LOADR(1) LOADR(2) LOADR(3) LOADR(4) LOADR(5) LOADR(6)
        BODY(0) BODY(1) BODY(2) BODY(3) BODY(4) BODY(5) BODY(6)
    }

    // ---- reduction: wave shuffle (double) -> LDS -> one atomic per block ----
    double local = (double)ssum;
    #pragma unroll
    for (int off = 32; off > 0; off >>= 1)
        local += __shfl_down(local, off, 64);
    __shared__ double wsum[WPB];
    if (lane == 0) wsum[w] = local;
    __syncthreads();
    if (threadIdx.x == 0) {
        double tot = 0.0;
        #pragma unroll
        for (int k = 0; k < WPB; ++k) tot += wsum[k];
        atomicAdd(acc, tot);
        __threadfence();
        unsigned ticket = atomicAdd(counter, 1u);
        if (ticket == NBLK - 1) {
            double stot = atomicAdd(acc, 0.0);   // device-scope coherent read
            const double N = (double)BB * (double)OHEI * (double)OWID;
            out[0] = (float)(1.0 - stot / N);
        }
    }
}

extern "C" void kernel_launch(void* const* d_in, const int* in_sizes, int n_in,
                              void* d_out, int out_size, void* d_ws, size_t ws_size,
                              hipStream_t stream)
{
    const float* X  = (const float*)d_in[0];
    const float* Y  = (const float*)d_in[1];
    const float* dr = (const float*)d_in[2];
    // d_in[3] is the box kernel w (all 1/49) — folded into constants.
    double*   acc     = (double*)d_ws;
    unsigned* counter = (unsigned*)((char*)d_ws + 8);
    float*    out     = (float*)d_out;

    hipMemsetAsync(d_ws, 0, 16, stream);
    ssim_main<<<dim3(NBLK), dim3(NTH), 0, stream>>>(X, Y, dr, acc, counter, out);
}